// Round 1
// 1394.836 us; speedup vs baseline: 1.2911x; 1.2911x over previous
//
#include <hip/hip_runtime.h>
#include <math.h>

#define NB  256
#define T   1024
#define DIN 64
#define H   128
#define G4  512

typedef __attribute__((ext_vector_type(8))) short    bf16x8;
typedef __attribute__((ext_vector_type(4))) float    f32x4;
typedef __attribute__((ext_vector_type(8))) _Float16 f16x8;

#define DPPQ(v, CTRL) __int_as_float(__builtin_amdgcn_update_dpp(0, __float_as_int(v), (CTRL), 0xf, 0xf, true))

__device__ __forceinline__ float sigf(float x)   { return 1.0f / (1.0f + __expf(-x)); }
__device__ __forceinline__ float tanhf_(float x) { return 2.0f / (1.0f + __expf(-2.0f * x)) - 1.0f; }

__device__ __forceinline__ void split_bf16(float x, short& hi, short& lo) {
    unsigned u = __float_as_uint(x);
    unsigned hb = (u + 0x7fffu + ((u >> 16) & 1u)) >> 16;
    hi = (short)hb;
    float r = x - __uint_as_float(hb << 16);
    unsigned u2 = __float_as_uint(r);
    lo = (short)((u2 + 0x7fffu + ((u2 >> 16) & 1u)) >> 16);
}

struct SJ {                       // one scan job (one layer, one time tile)
    const _Float16* xg;           // [NB*TILE][512] gate' order, f16, no bias
    const float* whh;             // [512][128] original gate order
    const float* bias;            // [512] original order
    const float* h0;              // [NB][128] initial h for this layer
    float* sth; float* stc;       // [NB][128] carried state
    short* hh; short* hl;         // layer0: [NB*TILE][128] bf16 hi/lo planes (else null)
    int first;                    // t0 == 0 ?
    int dofc;                     // fuse final FC (layer1 last tile)
};

// ---------------------------------------------------------------------------
// Dual-job recurrent scan, MFMA matvec. grid = nbA + nbB blocks, 512 thr.
// Per wave: gate' columns 64w..64w+63 as 4 MFMA N-tiles, two independent
// 2-deep accumulate chains. Each lane applies ITS OWN gate's nonlinearity
// (unified sig/tanh form, per-thread constants) BEFORE the quad DPP
// broadcast: 4 trans ops/lane/step instead of 10. ONE barrier per step.
// Layer-0 h output written as bf16 hi/lo planes (pre-split for the GEMM).
// ---------------------------------------------------------------------------
template<int TILE>
__global__ __launch_bounds__(512, 4)
void scan2(SJ ja, SJ jb, int nbA,
           const float* __restrict__ fcw, const float* __restrict__ fcb,
           float* __restrict__ out)
{
    __shared__ _Float16 __align__(16) lds_h[2][H];   // 512 B
    __shared__ float lds_r[H];

    const int bid = blockIdx.x;
    const bool isA = bid < nbA;
    const SJ J = isA ? ja : jb;
    const int b = isA ? bid : bid - nbA;

    const int t    = threadIdx.x;
    const int lane = t & 63;
    const int w    = t >> 6;
    const int kg   = t & 3;
    const int hu   = t >> 2;
    const int kt_grp = lane >> 4;        // k-subgroup 0..3 within frag

    // B fragments: wfrag[j][kt] = W_hh[gate' col n][k], n = 64w+16j+(lane&15),
    // k = 32*kt + kt_grp*8 + jj  (16x16x32 f16 B-operand layout)
    f16x8 wfrag[4][4];
    #pragma unroll
    for (int j = 0; j < 4; ++j) {
        const int n  = 64 * w + 16 * j + (lane & 15);
        const int pn = (n & 3) * 128 + (n >> 2);     // original gate row
        const float* wr = J.whh + (size_t)pn * H;
        #pragma unroll
        for (int kt = 0; kt < 4; ++kt) {
            const int base = 32 * kt + kt_grp * 8;
            float4 v0 = *(const float4*)(wr + base);
            float4 v1 = *(const float4*)(wr + base + 4);
            wfrag[j][kt] = (f16x8){(_Float16)v0.x, (_Float16)v0.y, (_Float16)v0.z, (_Float16)v0.w,
                                   (_Float16)v1.x, (_Float16)v1.y, (_Float16)v1.z, (_Float16)v1.w};
        }
    }
    const float bj = J.bias[kg * 128 + hu];   // gate' t -> original row (t&3)*128+(t>>2)

    // per-thread nonlinearity constants: kg==2 is the cell (tanh) gate
    const bool  isg = (kg == 2);
    const float nsc = isg ? -2.0f : -1.0f;
    const float va  = isg ?  2.0f :  1.0f;
    const float vb  = isg ? -1.0f :  0.0f;

    if (t < H) {
        float hv = J.first ? J.h0[(size_t)b * H + t] : J.sth[(size_t)b * H + t];
        lds_h[0][t] = (_Float16)hv;
    }
    float c = J.first ? 0.0f : J.stc[(size_t)b * H + hu];
    __syncthreads();

    const _Float16* xgb = J.xg + (size_t)b * TILE * G4 + t;
    float xv0 = (float)xgb[0];
    float xv1 = (TILE > 1) ? (float)xgb[G4] : 0.0f;

    const bool s4 = (lane & 16) != 0;
    const bool s5 = (lane & 32) != 0;

    float hreg = 0.0f;
    int cur = 0;

    for (int tt = 0; tt < TILE; ++tt) {
        // A fragments: h broadcast over M; af[kt][jj] = h[32kt + kt_grp*8 + jj]
        const _Float16* hb = &lds_h[cur][0];
        f16x8 af0 = *(const f16x8*)(hb +  0 + kt_grp * 8);
        f16x8 af1 = *(const f16x8*)(hb + 32 + kt_grp * 8);
        f16x8 af2 = *(const f16x8*)(hb + 64 + kt_grp * 8);
        f16x8 af3 = *(const f16x8*)(hb + 96 + kt_grp * 8);

        const f32x4 z = (f32x4){0.f, 0.f, 0.f, 0.f};
        // two independent 2-deep chains (kt 0,1) and (kt 2,3)
        f32x4 a0 = __builtin_amdgcn_mfma_f32_16x16x32_f16(af0, wfrag[0][0], z, 0, 0, 0);
        f32x4 a1 = __builtin_amdgcn_mfma_f32_16x16x32_f16(af0, wfrag[1][0], z, 0, 0, 0);
        f32x4 a2 = __builtin_amdgcn_mfma_f32_16x16x32_f16(af0, wfrag[2][0], z, 0, 0, 0);
        f32x4 a3 = __builtin_amdgcn_mfma_f32_16x16x32_f16(af0, wfrag[3][0], z, 0, 0, 0);
        f32x4 b0 = __builtin_amdgcn_mfma_f32_16x16x32_f16(af2, wfrag[0][2], z, 0, 0, 0);
        f32x4 b1 = __builtin_amdgcn_mfma_f32_16x16x32_f16(af2, wfrag[1][2], z, 0, 0, 0);
        f32x4 b2 = __builtin_amdgcn_mfma_f32_16x16x32_f16(af2, wfrag[2][2], z, 0, 0, 0);
        f32x4 b3 = __builtin_amdgcn_mfma_f32_16x16x32_f16(af2, wfrag[3][2], z, 0, 0, 0);
        a0 = __builtin_amdgcn_mfma_f32_16x16x32_f16(af1, wfrag[0][1], a0, 0, 0, 0);
        a1 = __builtin_amdgcn_mfma_f32_16x16x32_f16(af1, wfrag[1][1], a1, 0, 0, 0);
        a2 = __builtin_amdgcn_mfma_f32_16x16x32_f16(af1, wfrag[2][1], a2, 0, 0, 0);
        a3 = __builtin_amdgcn_mfma_f32_16x16x32_f16(af1, wfrag[3][1], a3, 0, 0, 0);
        b0 = __builtin_amdgcn_mfma_f32_16x16x32_f16(af3, wfrag[0][3], b0, 0, 0, 0);
        b1 = __builtin_amdgcn_mfma_f32_16x16x32_f16(af3, wfrag[1][3], b1, 0, 0, 0);
        b2 = __builtin_amdgcn_mfma_f32_16x16x32_f16(af3, wfrag[2][3], b2, 0, 0, 0);
        b3 = __builtin_amdgcn_mfma_f32_16x16x32_f16(af3, wfrag[3][3], b3, 0, 0, 0);

        // gate' (64w + lane) = N-tile (lane>>4), col (lane&15); any acc row
        float gloA = s4 ? a1[0] : a0[0];
        float ghiA = s4 ? a3[0] : a2[0];
        float gloB = s4 ? b1[0] : b0[0];
        float ghiB = s4 ? b3[0] : b2[0];
        float g = (s5 ? ghiA : gloA) + (s5 ? ghiB : gloB) + xv0 + bj;

        xv0 = xv1;
        int tn = (tt + 2 < TILE) ? (tt + 2) : (TILE - 1);
        xv1 = (float)xgb[(size_t)tn * G4];

        // own-gate nonlinearity (2 trans), then quad broadcast of activated vals
        float u  = 1.0f / (1.0f + __expf(nsc * g));
        float vl = fmaf(u, va, vb);          // sig for i/f/o, tanh for cell gate

        float ni = DPPQ(vl, 0x00);
        float nf = DPPQ(vl, 0x55);
        float ng = DPPQ(vl, 0xAA);
        float no = DPPQ(vl, 0xFF);

        c = nf * c + ni * ng;
        float h = no * tanhf_(c);            // 2 trans (redundant across quad)
        hreg = h;

        if (kg == 0) {
            lds_h[cur ^ 1][hu] = (_Float16)h;
            if (J.hh) {
                short hs, ls; split_bf16(h, hs, ls);
                size_t ix = ((size_t)b * TILE + tt) * H + hu;
                J.hh[ix] = hs; J.hl[ix] = ls;
            }
        }
        cur ^= 1;
        __syncthreads();
    }

    if (kg == 0) {
        J.sth[(size_t)b * H + hu] = hreg;
        J.stc[(size_t)b * H + hu] = c;
    }

    if (J.dofc) {
        if (kg == 0) lds_r[hu] = hreg * fcw[hu];
        __syncthreads();
        if (t == 0) {
            float s = fcb[0];
            for (int k = 0; k < H; ++k) s += lds_r[k];
            out[b] = s;
        }
    }
}

// ---------------------------------------------------------------------------
// Prep: split x and the (gate'-permuted) W_ih matrices into bf16 hi/lo
// planes once. Memory-bound, runs once per call.
// ---------------------------------------------------------------------------
__global__ __launch_bounds__(256)
void prep(const float* __restrict__ x,
          const float* __restrict__ wih0, const float* __restrict__ wih1,
          short* __restrict__ Xh, short* __restrict__ Xl,
          short* __restrict__ W0h, short* __restrict__ W0l,
          short* __restrict__ W1h, short* __restrict__ W1l)
{
    const int NX4 = NB * T * DIN / 4;
    int gid = blockIdx.x * blockDim.x + threadIdx.x;
    int gs  = gridDim.x * blockDim.x;
    for (int i = gid; i < NX4; i += gs) {
        float4 v = ((const float4*)x)[i];
        short h0s, l0s, h1s, l1s, h2s, l2s, h3s, l3s;
        split_bf16(v.x, h0s, l0s); split_bf16(v.y, h1s, l1s);
        split_bf16(v.z, h2s, l2s); split_bf16(v.w, h3s, l3s);
        *(short4*)&Xh[4 * i] = make_short4(h0s, h1s, h2s, h3s);
        *(short4*)&Xl[4 * i] = make_short4(l0s, l1s, l2s, l3s);
    }
    for (int i = gid; i < 512 * 64; i += gs) {
        int np = i >> 6, k = i & 63;
        int pn = (np & 3) * 128 + (np >> 2);
        short hs, ls; split_bf16(wih0[pn * 64 + k], hs, ls);
        W0h[i] = hs; W0l[i] = ls;
    }
    for (int i = gid; i < 512 * 128; i += gs) {
        int np = i >> 7, k = i & 127;
        int pn = (np & 3) * 128 + (np >> 2);
        short hs, ls; split_bf16(wih1[pn * 128 + k], hs, ls);
        W1h[i] = hs; W1l[i] = ls;
    }
}

// ---------------------------------------------------------------------------
// MFMA GEMM: Out[r][n'] = sum_k A[r][k] * W[n'][k]; all operands pre-split
// bf16 hi/lo planes (W pre-permuted to gate' order). 3-term bf16 product.
// Dual-job launch; tile 128x128, BK=64. Output f16.
// ---------------------------------------------------------------------------
struct GJ {
    const short* Ah; const short* Al;   // [rows][K] bf16 planes
    const short* Wh; const short* Wl;   // [512][K] bf16, gate'-permuted
    _Float16* O;                        // [rows][512] f16
    int K, Astride, t0;
};

__global__ __launch_bounds__(256, 2)
void gemm_xg(GJ ja, GJ jb, int nbA, int lgT, int lgM)
{
    __shared__ short sAh[128][72], sAl[128][72], sWh[128][72], sWl[128][72];

    int bid = blockIdx.x;
    const GJ J = (bid < nbA) ? ja : jb;
    if (bid >= nbA) bid -= nbA;

    const int Mmask = (1 << lgM) - 1;
    const int m0 = (bid & Mmask) << 7;
    const int n0 = (bid >> lgM) << 7;
    const int Tmask = (1 << lgT) - 1;

    const int j = threadIdx.x;
    const int lane = j & 63, wv = j >> 6;
    const int wm = wv >> 1, wn = wv & 1;
    const int q = lane >> 4, n16 = lane & 15;

    f32x4 acc[4][4];
    #pragma unroll
    for (int a = 0; a < 4; ++a)
        #pragma unroll
        for (int bq = 0; bq < 4; ++bq) acc[a][bq] = (f32x4){0.f, 0.f, 0.f, 0.f};

    const int npass = J.K >> 6;
    for (int kp = 0; kp < npass; ++kp) {
        #pragma unroll
        for (int it = 0; it < 4; ++it) {
            int c = j + it * 256;              // 1024 chunks of 8 bf16
            int r = c >> 3, kc = (c & 7) << 3;
            int gr = m0 + r;
            size_t arow = (size_t)(gr >> lgT) * J.Astride + J.t0 + (gr & Tmask);
            size_t aoff = arow * J.K + (size_t)kp * 64 + kc;
            *(bf16x8*)&sAh[r][kc] = *(const bf16x8*)(J.Ah + aoff);
            *(bf16x8*)&sAl[r][kc] = *(const bf16x8*)(J.Al + aoff);
            size_t woff = (size_t)(n0 + r) * J.K + (size_t)kp * 64 + kc;
            *(bf16x8*)&sWh[r][kc] = *(const bf16x8*)(J.Wh + woff);
            *(bf16x8*)&sWl[r][kc] = *(const bf16x8*)(J.Wl + woff);
        }
        __syncthreads();

        #pragma unroll
        for (int kt = 0; kt < 2; ++kt) {
            const int kk = kt * 32 + q * 8;
            bf16x8 ah[4], al[4];
            #pragma unroll
            for (int mt = 0; mt < 4; ++mt) {
                int row = wm * 64 + mt * 16 + n16;
                ah[mt] = *(const bf16x8*)&sAh[row][kk];
                al[mt] = *(const bf16x8*)&sAl[row][kk];
            }
            #pragma unroll
            for (int nt = 0; nt < 4; ++nt) {
                int col = wn * 64 + nt * 16 + n16;
                bf16x8 bh = *(const bf16x8*)&sWh[col][kk];
                bf16x8 bl = *(const bf16x8*)&sWl[col][kk];
                #pragma unroll
                for (int mt = 0; mt < 4; ++mt) {
                    acc[mt][nt] = __builtin_amdgcn_mfma_f32_16x16x32_bf16(ah[mt], bh, acc[mt][nt], 0, 0, 0);
                    acc[mt][nt] = __builtin_amdgcn_mfma_f32_16x16x32_bf16(al[mt], bh, acc[mt][nt], 0, 0, 0);
                    acc[mt][nt] = __builtin_amdgcn_mfma_f32_16x16x32_bf16(ah[mt], bl, acc[mt][nt], 0, 0, 0);
                }
            }
        }
        __syncthreads();
    }

    #pragma unroll
    for (int mt = 0; mt < 4; ++mt) {
        #pragma unroll
        for (int nt = 0; nt < 4; ++nt) {
            int row = m0 + wm * 64 + mt * 16 + q * 4;
            int col = n0 + wn * 64 + nt * 16 + n16;
            #pragma unroll
            for (int r = 0; r < 4; ++r)
                J.O[(size_t)(row + r) * G4 + col] = (_Float16)acc[mt][nt][r];
        }
    }
}

template<int TILE>
static void run_all(const float* x, const float* h0,
                    const float* wih0, const float* whh0, const float* b0,
                    const float* wih1, const float* whh1, const float* b1,
                    const float* fcw, const float* fcb, float* out,
                    void* d_ws, hipStream_t stream)
{
    const int n_t = T / TILE;
    const int lgT = __builtin_ctz(TILE);
    const int lgM = lgT + 1;
    const int nbJ = 8 * TILE;   // (NB*TILE/128) * (512/128)

    // workspace carve (st first: f32; rest 2-byte types, all sizes 16B-multiples)
    float*    st  = (float*)d_ws;                              // 4*NB*H
    _Float16* xg0 = (_Float16*)(st + 4 * NB * H);
    _Float16* xg1 = xg0 + (size_t)NB * TILE * G4;
    short*    hh  = (short*)(xg1 + (size_t)NB * TILE * G4);
    short*    hl  = hh + (size_t)NB * TILE * H;
    short*    Xh  = hl + (size_t)NB * TILE * H;
    short*    Xl  = Xh + (size_t)NB * T * DIN;
    short*    W0h = Xl + (size_t)NB * T * DIN;
    short*    W0l = W0h + 512 * 64;
    short*    W1h = W0l + 512 * 64;
    short*    W1l = W1h + 512 * 128;
    float *st_h0 = st, *st_c0 = st + NB * H, *st_h1 = st + 2 * NB * H, *st_c1 = st + 3 * NB * H;

    prep<<<2048, 256, 0, stream>>>(x, wih0, wih1, Xh, Xl, W0h, W0l, W1h, W1l);

    SJ l0, l1;
    l0.whh = whh0; l0.bias = b0; l0.h0 = h0;                  l0.sth = st_h0; l0.stc = st_c0;
    l0.xg = xg0;   l0.hh = hh;   l0.hl = hl;  l0.dofc = 0;
    l1.whh = whh1; l1.bias = b1; l1.h0 = h0 + (size_t)NB * H; l1.sth = st_h1; l1.stc = st_c1;
    l1.xg = xg1;   l1.hh = nullptr; l1.hl = nullptr;

    GJ g0; g0.Ah = Xh; g0.Al = Xl; g0.Wh = W0h; g0.Wl = W0l; g0.O = xg0; g0.K = DIN; g0.Astride = T;    g0.t0 = 0;
    GJ g1; g1.Ah = hh; g1.Al = hl; g1.Wh = W1h; g1.Wl = W1l; g1.O = xg1; g1.K = H;   g1.Astride = TILE; g1.t0 = 0;

    // xg0(0)
    gemm_xg<<<nbJ, 256, 0, stream>>>(g0, g0, nbJ, lgT, lgM);
    // scan_l0 tile 0 (solo)
    l0.first = 1;
    scan2<TILE><<<NB, 512, 0, stream>>>(l0, l0, NB, fcw, fcb, out);

    for (int k = 0; k < n_t; ++k) {
        if (k + 1 < n_t) {
            GJ ga = g1;                         // xg1(k) from hh/hl (tile k)
            GJ gb = g0; gb.t0 = (k + 1) * TILE; // xg0(k+1) from x
            gemm_xg<<<2 * nbJ, 256, 0, stream>>>(ga, gb, nbJ, lgT, lgM);
            // combined: scan_l0(k+1) || scan_l1(k)
            l0.first = 0;
            l1.first = (k == 0);
            l1.dofc = 0;
            scan2<TILE><<<2 * NB, 512, 0, stream>>>(l0, l1, NB, fcw, fcb, out);
        } else {
            gemm_xg<<<nbJ, 256, 0, stream>>>(g1, g1, nbJ, lgT, lgM);
            // final scan_l1 (solo, fused FC)
            l1.first = (k == 0);
            l1.dofc = 1;
            scan2<TILE><<<NB, 512, 0, stream>>>(l1, l1, NB, fcw, fcb, out);
        }
    }
}

extern "C" void kernel_launch(void* const* d_in, const int* in_sizes, int n_in,
                              void* d_out, int out_size, void* d_ws, size_t ws_size,
                              hipStream_t stream)
{
    const float* x    = (const float*)d_in[0];
    const float* h0   = (const float*)d_in[1];
    const float* wih0 = (const float*)d_in[2];
    const float* whh0 = (const float*)d_in[3];
    const float* b0   = (const float*)d_in[4];
    const float* wih1 = (const float*)d_in[5];
    const float* whh1 = (const float*)d_in[6];
    const float* b1   = (const float*)d_in[7];
    const float* fcw  = (const float*)d_in[8];
    const float* fcb  = (const float*)d_in[9];
    float* out = (float*)d_out;

    int TILE = 256;
    while (TILE > 16) {
        size_t need = (size_t)4 * NB * H * 4                      // states
                    + (size_t)NB * TILE * (2 * G4 * 2 + 2 * H * 2) // xg f16 + h hi/lo
                    + (size_t)2 * NB * T * DIN * 2                 // x hi/lo
                    + (size_t)2 * (512 * 64 + 512 * 128) * 2;      // W hi/lo
        if (need <= ws_size) break;
        TILE >>= 1;
    }

    switch (TILE) {
        case 256: run_all<256>(x, h0, wih0, whh0, b0, wih1, whh1, b1, fcw, fcb, out, d_ws, stream); break;
        case 128: run_all<128>(x, h0, wih0, whh0, b0, wih1, whh1, b1, fcw, fcb, out, d_ws, stream); break;
        case  64: run_all< 64>(x, h0, wih0, whh0, b0, wih1, whh1, b1, fcw, fcb, out, d_ws, stream); break;
        default:  run_all< 32>(x, h0, wih0, whh0, b0, wih1, whh1, b1, fcw, fcb, out, d_ws, stream); break;
    }
}